// Round 1
// baseline (46.928 us; speedup 1.0000x reference)
//
#include <hip/hip_runtime.h>

#define NB 128
#define NQ 1000
#define NG 300
#define NK 4
#define THRESH 0.4f
#define GROUPS_PER_BLOCK 16   // 16-lane group per GT, 256 threads/block

// Candidate key: (float_bits(val) << 32) | ~q.
// All vals >= 0 so float bits are monotonic; ~q makes smaller q compare
// larger => u64 '>' implements (value desc, index asc) exactly like
// jax.lax.top_k's stable tie-breaking.

__global__ __launch_bounds__(256) void matcher_kernel(
    const float* __restrict__ logits,      // [B,Q,1]
    const float* __restrict__ pboxes,      // [B,Q,4]
    const float* __restrict__ tboxes,      // [B,G,4]
    float* __restrict__ out_vals,          // [B,G,K]
    float* __restrict__ out_idx,           // [B,G,K] (written as float)
    float* __restrict__ out_mask)          // [B,G,K] (written as 0/1 float)
{
    __shared__ float4 sbox[NQ];    // 16 KB
    __shared__ float  sscore[NQ];  //  4 KB

    const int b   = blockIdx.y;
    const int tid = threadIdx.x;

    // Stage this batch's pred boxes + sigmoid(score) into LDS.
    const float4* pb = reinterpret_cast<const float4*>(pboxes + (size_t)b * NQ * 4);
    for (int i = tid; i < NQ; i += 256) {
        sbox[i] = pb[i];
        float x = logits[(size_t)b * NQ + i];
        sscore[i] = 1.0f / (1.0f + expf(-x));
    }
    __syncthreads();

    const int group = tid >> 4;   // 0..15
    const int lane  = tid & 15;   // 0..15
    const int g = blockIdx.x * GROUPS_PER_BLOCK + group;

    unsigned long long k0 = 0ull, k1 = 0ull, k2 = 0ull, k3 = 0ull;

    if (g < NG) {
        const float4 tb =
            reinterpret_cast<const float4*>(tboxes + (size_t)b * NG * 4)[g];
        const float tarea = (tb.z - tb.x) * (tb.w - tb.y);

        for (int q = lane; q < NQ; q += GROUPS_PER_BLOCK) {
            float4 p = sbox[q];
            float parea = (p.z - p.x) * (p.w - p.y);
            float ltx = fmaxf(p.x, tb.x);
            float lty = fmaxf(p.y, tb.y);
            float rbx = fminf(p.z, tb.z);
            float rby = fminf(p.w, tb.w);
            float w = fmaxf(rbx - ltx, 0.0f);
            float h = fmaxf(rby - lty, 0.0f);
            float inter = w * h;
            float uni   = parea + tarea - inter;
            float iou   = inter / (uni + 1e-7f);
            float sc    = sscore[q];
            float val   = iou > THRESH ? sc * iou : 0.0f;

            unsigned long long ck =
                ((unsigned long long)__float_as_uint(val) << 32) |
                (unsigned long long)(unsigned)(~(unsigned)q);

            // Sorted-insert into k0>=k1>=k2>=k3 (keys are unique by index).
            if (ck > k3) {
                if (ck > k0)      { k3 = k2; k2 = k1; k1 = k0; k0 = ck; }
                else if (ck > k1) { k3 = k2; k2 = k1; k1 = ck; }
                else if (ck > k2) { k3 = k2; k2 = ck; }
                else              { k3 = ck; }
            }
        }
    }

    // Bitonic merge of sorted-4 lists across the 16-lane group.
    // [k0..k3 desc, p3..p0 asc] is bitonic; split keeps top-4 (bitonic),
    // then 4 compare-exchanges sort it desc.
#define MERGE_STEP(MASK)                                                    \
    {                                                                       \
        unsigned long long p0 = __shfl_xor(k0, MASK, 64);                   \
        unsigned long long p1 = __shfl_xor(k1, MASK, 64);                   \
        unsigned long long p2 = __shfl_xor(k2, MASK, 64);                   \
        unsigned long long p3 = __shfl_xor(k3, MASK, 64);                   \
        k0 = k0 > p3 ? k0 : p3;                                             \
        k1 = k1 > p2 ? k1 : p2;                                             \
        k2 = k2 > p1 ? k2 : p1;                                             \
        k3 = k3 > p0 ? k3 : p0;                                             \
        unsigned long long t;                                               \
        if (k0 < k2) { t = k0; k0 = k2; k2 = t; }                           \
        if (k1 < k3) { t = k1; k1 = k3; k3 = t; }                           \
        if (k0 < k1) { t = k0; k0 = k1; k1 = t; }                           \
        if (k2 < k3) { t = k2; k2 = k3; k3 = t; }                           \
    }

    MERGE_STEP(1)
    MERGE_STEP(2)
    MERGE_STEP(4)
    MERGE_STEP(8)
#undef MERGE_STEP

    if (g < NG && lane < NK) {
        unsigned long long kk =
            lane == 0 ? k0 : lane == 1 ? k1 : lane == 2 ? k2 : k3;
        float v  = __uint_as_float((unsigned)(kk >> 32));
        int   qi = (int)(~(unsigned)kk);
        size_t o = ((size_t)b * NG + g) * NK + lane;
        out_vals[o] = v;
        out_idx[o]  = (float)qi;
        out_mask[o] = v > 0.0f ? 1.0f : 0.0f;
    }
}

extern "C" void kernel_launch(void* const* d_in, const int* in_sizes, int n_in,
                              void* d_out, int out_size, void* d_ws, size_t ws_size,
                              hipStream_t stream) {
    const float* logits = (const float*)d_in[0];  // [128,1000,1]
    const float* pboxes = (const float*)d_in[1];  // [128,1000,4]
    const float* tboxes = (const float*)d_in[2];  // [128,300,4]

    float* out      = (float*)d_out;
    const size_t bgk = (size_t)NB * NG * NK;      // 153600
    float* out_vals = out;
    float* out_idx  = out + bgk;
    float* out_mask = out + 2 * bgk;

    dim3 grid((NG + GROUPS_PER_BLOCK - 1) / GROUPS_PER_BLOCK, NB);  // (19,128)
    matcher_kernel<<<grid, 256, 0, stream>>>(logits, pboxes, tboxes,
                                             out_vals, out_idx, out_mask);
}

// Round 2
// 39.840 us; speedup vs baseline: 1.1779x; 1.1779x over previous
//
#include <hip/hip_runtime.h>

#define NB 128
#define NQ 1000
#define NQPAD 1024
#define NG 300
#define NK 4
#define THRESH 0.4f
#define GROUPS_PER_BLOCK 16   // 16-lane group per GT, 256 threads/block

// Candidate key: (float_bits(val) << 32) | ~q, val > 0 only.
// All vals > 0 so float bits are monotonic; ~q makes smaller q compare
// larger => u64 '>' implements (value desc, index asc) exactly like
// jax.lax.top_k's stable tie-breaking. Key 0 == empty slot.

__global__ __launch_bounds__(256) void matcher_kernel(
    const float* __restrict__ logits,      // [B,Q,1]
    const float* __restrict__ pboxes,      // [B,Q,4]
    const float* __restrict__ tboxes,      // [B,G,4]
    float* __restrict__ out_vals,          // [B,G,K]
    float* __restrict__ out_idx,           // [B,G,K] (written as float)
    float* __restrict__ out_mask)          // [B,G,K] (written as 0/1 float)
{
    __shared__ float4 sbox[NQPAD];    // 16 KB
    __shared__ float  sscore[NQPAD];  //  4 KB

    const int b   = blockIdx.y;
    const int tid = threadIdx.x;

    // Stage this batch's pred boxes + sigmoid(score) into LDS; pad with
    // degenerate far-away boxes (inter = 0, never passes prefilter).
    const float4* pb = reinterpret_cast<const float4*>(pboxes + (size_t)b * NQ * 4);
    for (int i = tid; i < NQPAD; i += 256) {
        float4 bx;
        float  s;
        if (i < NQ) {
            bx = pb[i];
            float x = logits[(size_t)b * NQ + i];
            s = 1.0f / (1.0f + expf(-x));
        } else {
            bx = make_float4(9e8f, 9e8f, 9e8f, 9e8f);
            s = 0.0f;
        }
        sbox[i]   = bx;
        sscore[i] = s;
    }
    __syncthreads();

    const int group = tid >> 4;   // 0..15
    const int lane  = tid & 15;   // 0..15
    const int g = blockIdx.x * GROUPS_PER_BLOCK + group;

    unsigned long long k0 = 0ull, k1 = 0ull, k2 = 0ull, k3 = 0ull;

    if (g < NG) {
        const float4 tb =
            reinterpret_cast<const float4*>(tboxes + (size_t)b * NG * 4)[g];
        const float tarea = (tb.z - tb.x) * (tb.w - tb.y);
        // Conservative prefilter: iou > 0.4 => inter > 0.4*tarea (union >=
        // tarea). 0.398 gives 0.5% margin >> any f32 rounding, so no true
        // positive can be rejected here; borderline cases go to the exact
        // reference-identical slow path below.
        const float sthr = 0.398f * tarea;

#pragma unroll 4
        for (int it = 0; it < NQPAD / GROUPS_PER_BLOCK; ++it) {
            const int q = lane + it * GROUPS_PER_BLOCK;
            float4 p = sbox[q];
            float ltx = fmaxf(p.x, tb.x);
            float lty = fmaxf(p.y, tb.y);
            float rbx = fminf(p.z, tb.z);
            float rby = fminf(p.w, tb.w);
            float w = fmaxf(rbx - ltx, 0.0f);
            float h = fmaxf(rby - lty, 0.0f);
            float inter = w * h;

            if (__any(inter > sthr)) {
                // Exact, reference-identical value computation (full IEEE
                // division, same epsilon, same op order as numpy).
                float parea = (p.z - p.x) * (p.w - p.y);
                float uni   = parea + tarea - inter;
                float iou   = inter / (uni + 1e-7f);
                unsigned long long ck = 0ull;
                if (iou > THRESH) {
                    float sc  = sscore[q];
                    float val = sc * iou;
                    ck = ((unsigned long long)__float_as_uint(val) << 32) |
                         (unsigned long long)(unsigned)(~(unsigned)q);
                }
                if (__any(ck > k3)) {
                    if (ck > k3) {
                        if (ck > k0)      { k3 = k2; k2 = k1; k1 = k0; k0 = ck; }
                        else if (ck > k1) { k3 = k2; k2 = k1; k1 = ck; }
                        else if (ck > k2) { k3 = k2; k2 = ck; }
                        else              { k3 = ck; }
                    }
                }
            }
        }
    }

    // Bitonic merge of sorted-4 lists across the 16-lane group.
    // Empty slots (key 0) sort to the bottom naturally.
#define MERGE_STEP(MASK)                                                    \
    {                                                                       \
        unsigned long long p0 = __shfl_xor(k0, MASK, 64);                   \
        unsigned long long p1 = __shfl_xor(k1, MASK, 64);                   \
        unsigned long long p2 = __shfl_xor(k2, MASK, 64);                   \
        unsigned long long p3 = __shfl_xor(k3, MASK, 64);                   \
        k0 = k0 > p3 ? k0 : p3;                                             \
        k1 = k1 > p2 ? k1 : p2;                                             \
        k2 = k2 > p1 ? k2 : p1;                                             \
        k3 = k3 > p0 ? k3 : p0;                                             \
        unsigned long long t;                                               \
        if (k0 < k2) { t = k0; k0 = k2; k2 = t; }                           \
        if (k1 < k3) { t = k1; k1 = k3; k3 = t; }                           \
        if (k0 < k1) { t = k0; k0 = k1; k1 = t; }                           \
        if (k2 < k3) { t = k2; k2 = k3; k3 = t; }                           \
    }

    MERGE_STEP(1)
    MERGE_STEP(2)
    MERGE_STEP(4)
    MERGE_STEP(8)
#undef MERGE_STEP

    if (g < NG && lane < NK) {
        unsigned long long kk =
            lane == 0 ? k0 : lane == 1 ? k1 : lane == 2 ? k2 : k3;
        size_t o = ((size_t)b * NG + g) * NK + lane;
        if (kk != 0ull) {
            // Positive match.
            out_vals[o] = __uint_as_float((unsigned)(kk >> 32));
            out_idx[o]  = (float)(int)(~(unsigned)kk);
            out_mask[o] = 1.0f;
        } else {
            // Filler: value 0, mask 0, index = (lane-P)-th smallest query
            // index not in the positive set. P < 4 here, so k0..k2 hold ALL
            // positives of this GT (every lane has the full sorted result).
            int P = (int)(k0 != 0ull) + (int)(k1 != 0ull) +
                    (int)(k2 != 0ull) + (int)(k3 != 0ull);
            int q0 = (k0 != 0ull) ? (int)(~(unsigned)k0) : -1;
            int q1 = (k1 != 0ull) ? (int)(~(unsigned)k1) : -1;
            int q2 = (k2 != 0ull) ? (int)(~(unsigned)k2) : -1;
            int need = lane - P;   // 0-based rank among zero-fillers
            int cnt = 0;
            int qf = 0;
            for (int q = 0; q < 8; ++q) {
                if (q != q0 && q != q1 && q != q2) {
                    if (cnt == need) { qf = q; break; }
                    ++cnt;
                }
            }
            out_vals[o] = 0.0f;
            out_idx[o]  = (float)qf;
            out_mask[o] = 0.0f;
        }
    }
}

extern "C" void kernel_launch(void* const* d_in, const int* in_sizes, int n_in,
                              void* d_out, int out_size, void* d_ws, size_t ws_size,
                              hipStream_t stream) {
    const float* logits = (const float*)d_in[0];  // [128,1000,1]
    const float* pboxes = (const float*)d_in[1];  // [128,1000,4]
    const float* tboxes = (const float*)d_in[2];  // [128,300,4]

    float* out      = (float*)d_out;
    const size_t bgk = (size_t)NB * NG * NK;      // 153600
    float* out_vals = out;
    float* out_idx  = out + bgk;
    float* out_mask = out + 2 * bgk;

    dim3 grid((NG + GROUPS_PER_BLOCK - 1) / GROUPS_PER_BLOCK, NB);  // (19,128)
    matcher_kernel<<<grid, 256, 0, stream>>>(logits, pboxes, tboxes,
                                             out_vals, out_idx, out_mask);
}